// Round 14
// baseline (299.144 us; speedup 1.0000x reference)
//
#include <hip/hip_runtime.h>
#include <stdint.h>

// Sparse strided conv: scatter (features@W1 -> grid) + gather (grid@W2 -> out).
// R14: manual software pipelining of the random-gather loops (R13 counters
//      showed ~400cy/iter = one un-hidden gather; VGPR=32 proved the compiler
//      did no pipelining):
//   - scatter_o: preload all 27 inv_t values, depth-3 ring buffer of feat
//     fragments (statically indexed under full unroll).
//   - gather_v: 16 vox/wave, preload 27 row-ids, depth-3 ring of grid frags.
//   - k_inv fused into k_rows_fix (same iteration space, one less 13MB pass).

#define N_VOX 120000
#define IC 32
#define OC 64
#define NKV 27
#define DZ 21
#define HY 200
#define WX 176
#define TBL_BITS 20
#define TBL_SIZE (1 << TBL_BITS)
#define TBL_MASK (TBL_SIZE - 1)
#define MAXROWS 480000
#define SPILLCAP 65536

// ws layout (bytes); R1 passing proved ws_size >= 144,228,864
#define OFF_KEYS 0                 // 4,194,304
#define OFF_VALS 4194304           // 4,194,304
#define OFF_CNT 8388608            // 256 (cnt[0]=rows, cnt[1]=spill)
#define OFF_ROWS 8388864           // 12,960,000
#define OFF_FEATB 21348864         // 7,680,000
#define OFF_W2T 29028864           // 110,592
#define OFF_W1T 29139456           // 110,592
#define OFF_SPILL 29250048         // 524,288
#define OFF_INV 29774336           // 51,840,000 (inv_t[27][MAXROWS])
#define OFF_GRID 81614336          // 61,440,000
#define WS_NEEDED (OFF_GRID + (size_t)MAXROWS * OC * 2)  // 143,054,336

typedef __attribute__((ext_vector_type(8))) short short8;
typedef __attribute__((ext_vector_type(4))) float f32x4;

__device__ __forceinline__ uint32_t hash_lin(int lin) {
    return ((uint32_t)lin * 2654435761u) >> (32 - TBL_BITS);
}

__device__ __forceinline__ void atomPkBf16(uint16_t* p, uint32_t v) {
    asm volatile("global_atomic_pk_add_bf16 %0, %1, off" :: "v"(p), "v"(v) : "memory");
}

// RTNE f32 -> bf16 pair pack
__device__ __forceinline__ uint32_t pk_bf16(float a, float b) {
    uint32_t x = __float_as_uint(a), y = __float_as_uint(b);
    x = (x + 0x7fffu + ((x >> 16) & 1u)) >> 16;
    y = (y + 0x7fffu + ((y >> 16) & 1u)) >> 16;
    return x | (y << 16);
}
__device__ __forceinline__ uint16_t f2bf(float a) {
    uint32_t x = __float_as_uint(a);
    return (uint16_t)((x + 0x7fffu + ((x >> 16) & 1u)) >> 16);
}
__device__ __forceinline__ float bf2f(uint16_t u) {
    return __uint_as_float(((uint32_t)u) << 16);
}

__global__ void k_init(int* keys, int* counter,
                       const float2* __restrict__ feat2, uint32_t* featb,
                       const float* __restrict__ W1, uint16_t* w1t,
                       const float* __restrict__ W2, uint16_t* w2t) {
    int i = blockIdx.x * blockDim.x + threadIdx.x;
    int stride = gridDim.x * blockDim.x;
    for (int j = i; j < TBL_SIZE; j += stride) keys[j] = -1;
    for (int j = i; j < N_VOX * IC / 2; j += stride) {
        float2 f = feat2[j];
        featb[j] = pk_bf16(f.x, f.y);
    }
    // W1 [kv][c][o] f32 -> w1t [kv][o][c] bf16
    for (int j = i; j < NKV * IC * OC; j += stride) {
        int kv = j >> 11, c = (j >> 6) & 31, o = j & 63;
        w1t[(kv << 11) + (o << 5) + c] = f2bf(W1[j]);
    }
    // W2 [kv][o][c] f32 -> w2t [kv][c][o] bf16
    for (int j = i; j < NKV * OC * IC; j += stride) {
        int kv = j >> 11, o = (j >> 5) & 63, c = j & 31;
        w2t[(kv << 11) + (c << 6) + o] = f2bf(W2[j]);
    }
    if (i == 0) { counter[0] = 0; counter[1] = 0; }
}

__global__ void k_build(const int* __restrict__ coors, int* keys, int* rows) {
    int v = blockIdx.x * blockDim.x + threadIdx.x;
    if (v >= N_VOX) return;
    int b = coors[v * 4 + 0];
    int z = coors[v * 4 + 1];
    int y = coors[v * 4 + 2];
    int x = coors[v * 4 + 3];
#pragma unroll
    for (int kv = 0; kv < NKV; ++kv) {
        int oz = kv / 9, oy = (kv / 3) % 3, ox = kv % 3;
        int az = z + 1 - oz, ay = y + 1 - oy, ax = x + 1 - ox;
        int slot = -1;
        bool valid = (az >= 0) && !(az & 1) && ((az >> 1) < DZ) &&
                     (ay >= 0) && !(ay & 1) && ((ay >> 1) < HY) &&
                     (ax >= 0) && !(ax & 1) && ((ax >> 1) < WX);
        if (valid) {
            int lin = ((b * DZ + (az >> 1)) * HY + (ay >> 1)) * WX + (ax >> 1);
            uint32_t h = hash_lin(lin);
            for (;;) {
                int k = atomicCAS(&keys[h], -1, lin);
                if (k == -1 || k == lin) { slot = (int)h; break; }
                h = (h + 1) & TBL_MASK;
            }
        }
        rows[kv * N_VOX + v] = slot;
    }
}

// Block-aggregated compaction (1 atomic/block) + fused init of the block's
// claimed rows' inv_t entries to -1 (27 contiguous runs, one per kv).
__global__ __launch_bounds__(256) void k_assign(const int* __restrict__ keys,
                                                int* __restrict__ vals,
                                                int* counter,
                                                int* __restrict__ invt) {
    const int t = threadIdx.x;
    const int s0 = blockIdx.x * 2048 + t * 8;
    const int4 a = ((const int4*)(keys + s0))[0];
    const int4 b = ((const int4*)(keys + s0))[1];
    int k[8] = {a.x, a.y, a.z, a.w, b.x, b.y, b.z, b.w};
    int c = 0;
#pragma unroll
    for (int i = 0; i < 8; ++i) c += (k[i] != -1);

    __shared__ int sc[256];
    __shared__ int base;
    sc[t] = c;
    __syncthreads();
#pragma unroll
    for (int d = 1; d < 256; d <<= 1) {
        int y = (t >= d) ? sc[t - d] : 0;
        __syncthreads();
        sc[t] += y;
        __syncthreads();
    }
    if (t == 255) base = atomicAdd(&counter[0], sc[255]);
    __syncthreads();
    const int total = sc[255];
    int r = base + sc[t] - c;  // exclusive prefix
#pragma unroll
    for (int i = 0; i < 8; ++i) {
        if (k[i] != -1) { vals[s0 + i] = (r < MAXROWS) ? r : -1; ++r; }
    }
    // init inv_t for claimed rows [base, base+total) across all 27 kv planes
    int zs = min(base, MAXROWS), ze = min(base + total, MAXROWS);
    for (int kv = 0; kv < NKV; ++kv)
        for (int i = zs + t; i < ze; i += 256) invt[kv * MAXROWS + i] = -1;
}

// rows slot->rowid rewrite FUSED with rulebook inversion (CAS; dupes spill).
__global__ void k_rows_fix(int* rows, const int* __restrict__ vals,
                           int* invt, int* spill, int* counter) {
    int i = blockIdx.x * blockDim.x + threadIdx.x;
    if (i >= NKV * N_VOX) return;
    int s = rows[i];
    int row = (s >= 0) ? vals[s] : -1;
    rows[i] = row;
    if (row >= 0) {
        int kv = i / N_VOX;
        int v = i - kv * N_VOX;
        int old = atomicCAS(&invt[kv * MAXROWS + row], -1, v);
        if (old != -1) {  // duplicate coords: second contributor to (row,kv)
            int sp = atomicAdd(&counter[1], 1);
            if (sp < SPILLCAP) {
                spill[2 * sp] = row;
                spill[2 * sp + 1] = (kv << 20) | v;
            }
        }
    }
}

// Scatter, OUTPUT-major MFMA, depth-3 pipelined. Wave owns 16 grid rows.
// All 27 inv_t values preloaded (coalesced, independent); feat-row fragment
// for kv+3 issued before kv's MFMAs (ring ap[4], static idx under unroll).
// D: col(li)=channel nt*16+li, row(lg*4+rg)=grid row.
__global__ __launch_bounds__(256) void k_scatter_o(
    const uint16_t* __restrict__ featb, const uint16_t* __restrict__ w1t,
    const int* __restrict__ invt, const int* __restrict__ counter,
    uint16_t* __restrict__ gridb) {
    const int wid = threadIdx.x >> 6;
    const int lane = threadIdx.x & 63;
    const int nrows = min(counter[0], MAXROWS);
    const int g0 = (blockIdx.x * 4 + wid) * 16;
    if (g0 >= nrows) return;
    const int lg = lane >> 4;
    const int li = lane & 15;
    const bool rowok = (g0 + li) < nrows;
    const short8 zz8 = {0, 0, 0, 0, 0, 0, 0, 0};

    int vv[NKV];
#pragma unroll
    for (int kv = 0; kv < NKV; ++kv)
        vv[kv] = rowok ? invt[(size_t)kv * MAXROWS + g0 + li] : -1;

    f32x4 acc[4] = {{0.f, 0.f, 0.f, 0.f}, {0.f, 0.f, 0.f, 0.f},
                    {0.f, 0.f, 0.f, 0.f}, {0.f, 0.f, 0.f, 0.f}};

    short8 ap[4];
#pragma unroll
    for (int j = 0; j < 3; ++j) {
        ap[j] = zz8;
        if (vv[j] >= 0)
            ap[j] = *(const short8*)(featb + (size_t)vv[j] * IC + lg * 8);
    }
#pragma unroll
    for (int kv = 0; kv < NKV; ++kv) {
        const int kp = kv + 3;
        if (kp < NKV) {
            ap[kp & 3] = zz8;
            if (vv[kp] >= 0)
                ap[kp & 3] = *(const short8*)(featb + (size_t)vv[kp] * IC + lg * 8);
        }
        if (__ballot(vv[kv] >= 0) != 0) {
            const uint16_t* w1k = w1t + (kv << 11);
#pragma unroll
            for (int nt = 0; nt < 4; ++nt) {
                const short8 b = *(const short8*)(w1k + (nt * 16 + li) * IC + lg * 8);
                acc[nt] = __builtin_amdgcn_mfma_f32_16x16x32_bf16(ap[kv & 3], b,
                                                                  acc[nt], 0, 0, 0);
            }
        }
    }
#pragma unroll
    for (int nt = 0; nt < 4; ++nt) {
#pragma unroll
        for (int rg = 0; rg < 4; ++rg) {
            const int g = g0 + lg * 4 + rg;
            float other = __shfl_xor(acc[nt][rg], 1, 64);
            if ((li & 1) == 0 && g < nrows) {
                *(uint32_t*)(gridb + (size_t)g * OC + nt * 16 + li) =
                    pk_bf16(acc[nt][rg], other);
            }
        }
    }
}

// Apply spilled (duplicate-coord) contributions atomically AFTER the store
// pass. ~600 entries expected; one wave per entry, lane = out channel.
__global__ void k_spill(const uint16_t* __restrict__ featb,
                        const uint16_t* __restrict__ w1t,
                        const int* __restrict__ spill,
                        const int* __restrict__ counter,
                        uint16_t* gridb) {
    const int nspill = min(counter[1], SPILLCAP);
    const int lane = threadIdx.x & 63;
    const int wstride = gridDim.x * (blockDim.x >> 6);
    for (int s = blockIdx.x * (blockDim.x >> 6) + (threadIdx.x >> 6);
         s < nspill; s += wstride) {
        const int row = spill[2 * s];
        const int kvv = spill[2 * s + 1];
        const int kv = kvv >> 20;
        const int v = kvv & 0xFFFFF;
        const uint16_t* f = featb + (size_t)v * IC;
        const uint16_t* wr = w1t + (kv << 11) + lane * IC;
        float acc = 0.f;
#pragma unroll
        for (int c = 0; c < IC; ++c) acc += bf2f(f[c]) * bf2f(wr[c]);
        float other = __shfl_xor(acc, 1, 64);
        if ((lane & 1) == 0)
            atomPkBf16(gridb + (size_t)row * OC + lane, pk_bf16(acc, other));
    }
}

// Gather, v-major MFMA, depth-3 pipelined. Wave owns 16 voxels; all 27
// row-ids preloaded (coalesced); grid-row fragments (a0,a1) for kv+3 issued
// before kv's MFMAs (rings a0p[4]/a1p[4], static idx under unroll).
__global__ __launch_bounds__(256) void k_gather_v(
    const uint16_t* __restrict__ gridb, const uint16_t* __restrict__ w2t,
    const int* __restrict__ rows, float* __restrict__ out) {
    const int wid = threadIdx.x >> 6;
    const int lane = threadIdx.x & 63;
    const int v0 = (blockIdx.x * 4 + wid) * 16;
    if (v0 >= N_VOX) return;
    const int lg = lane >> 4;
    const int li = lane & 15;
    const short8 zz8 = {0, 0, 0, 0, 0, 0, 0, 0};

    int rr[NKV];
#pragma unroll
    for (int kv = 0; kv < NKV; ++kv)
        rr[kv] = rows[kv * N_VOX + v0 + li];

    f32x4 acc[2] = {{0.f, 0.f, 0.f, 0.f}, {0.f, 0.f, 0.f, 0.f}};

    short8 a0p[4], a1p[4];
#pragma unroll
    for (int j = 0; j < 3; ++j) {
        a0p[j] = zz8;
        a1p[j] = zz8;
        if (rr[j] >= 0) {
            const uint16_t* gr = gridb + (size_t)rr[j] * OC;
            a0p[j] = *(const short8*)(gr + lg * 8);
            a1p[j] = *(const short8*)(gr + 32 + lg * 8);
        }
    }
#pragma unroll
    for (int kv = 0; kv < NKV; ++kv) {
        const int kp = kv + 3;
        if (kp < NKV) {
            a0p[kp & 3] = zz8;
            a1p[kp & 3] = zz8;
            if (rr[kp] >= 0) {
                const uint16_t* gr = gridb + (size_t)rr[kp] * OC;
                a0p[kp & 3] = *(const short8*)(gr + lg * 8);
                a1p[kp & 3] = *(const short8*)(gr + 32 + lg * 8);
            }
        }
        if (__ballot(rr[kv] >= 0) != 0) {
            const uint16_t* w2k = w2t + ((size_t)kv << 11);
#pragma unroll
            for (int nt = 0; nt < 2; ++nt) {
                const short8 b0 = *(const short8*)(w2k + (nt * 16 + li) * 64 + lg * 8);
                const short8 b1 = *(const short8*)(w2k + (nt * 16 + li) * 64 + 32 + lg * 8);
                acc[nt] = __builtin_amdgcn_mfma_f32_16x16x32_bf16(a0p[kv & 3], b0,
                                                                  acc[nt], 0, 0, 0);
                acc[nt] = __builtin_amdgcn_mfma_f32_16x16x32_bf16(a1p[kv & 3], b1,
                                                                  acc[nt], 0, 0, 0);
            }
        }
    }
#pragma unroll
    for (int nt = 0; nt < 2; ++nt)
#pragma unroll
        for (int rg = 0; rg < 4; ++rg) {
            const int v = v0 + lg * 4 + rg;
            out[(size_t)v * IC + nt * 16 + li] = acc[nt][rg];
        }
}

extern "C" void kernel_launch(void* const* d_in, const int* in_sizes, int n_in,
                              void* d_out, int out_size, void* d_ws, size_t ws_size,
                              hipStream_t stream) {
    const float* feat = (const float*)d_in[0];
    const int* coors = (const int*)d_in[1];
    const float* W1 = (const float*)d_in[2];
    const float* W2 = (const float*)d_in[3];
    float* out = (float*)d_out;

    if (ws_size < WS_NEEDED) return;  // loud failure: out stays poisoned

    char* ws = (char*)d_ws;
    int* keys = (int*)(ws + OFF_KEYS);
    int* vals = (int*)(ws + OFF_VALS);
    int* counter = (int*)(ws + OFF_CNT);
    int* rows = (int*)(ws + OFF_ROWS);
    uint32_t* featb = (uint32_t*)(ws + OFF_FEATB);
    uint16_t* w2t = (uint16_t*)(ws + OFF_W2T);
    uint16_t* w1t = (uint16_t*)(ws + OFF_W1T);
    int* spill = (int*)(ws + OFF_SPILL);
    int* invt = (int*)(ws + OFF_INV);
    uint16_t* gridb = (uint16_t*)(ws + OFF_GRID);

    k_init<<<dim3(4096), dim3(256), 0, stream>>>(keys, counter,
                                                 (const float2*)feat, featb,
                                                 W1, w1t, W2, w2t);
    k_build<<<dim3((N_VOX + 255) / 256), dim3(256), 0, stream>>>(coors, keys, rows);
    k_assign<<<dim3(TBL_SIZE / 2048), dim3(256), 0, stream>>>(keys, vals, counter,
                                                              invt);
    k_rows_fix<<<dim3((NKV * N_VOX + 255) / 256), dim3(256), 0, stream>>>(
        rows, vals, invt, spill, counter);
    // output-major scatter: 16 rows/wave, 4 waves/block over MAXROWS
    k_scatter_o<<<dim3(MAXROWS / 64), dim3(256), 0, stream>>>(
        (const uint16_t*)featb, w1t, invt, counter, gridb);
    k_spill<<<dim3(64), dim3(256), 0, stream>>>((const uint16_t*)featb, w1t,
                                                spill, counter, gridb);
    // gather: 16 vox/wave, 4 waves/block -> 1875 blocks
    k_gather_v<<<dim3(N_VOX / 64), dim3(256), 0, stream>>>(gridb, w2t, rows, out);
}

// Round 15
// 255.997 us; speedup vs baseline: 1.1685x; 1.1685x over previous
//
#include <hip/hip_runtime.h>
#include <stdint.h>

// Sparse strided conv: scatter (features@W1 -> grid) + gather (grid@W2 -> out).
// R15: scatter_o restructured around PACKED contributors (rows avg 1.1, cap 4):
//   - inv2[slot][row] (4 planes, entry=(kv<<20)|v) replaces invt[27][row]:
//     index read 39MB -> 7.7MB (R13 FETCH was 40MB, mostly invt).
//   - ALL <=4 feat rows preloaded into static regs upfront (latency paid once,
//     4 independent gathers) -> kv union loop is pure select+MFMA, no loads
//     gating MFMAs (R13/R14: one exposed ~400cy gather latency PER iteration).
//   - dup-kv + >4-contributor overflow -> spill list, atomic pk adds after.
//   gather_v reverted to R6/R13-proven 32-vox form (R14's 16-vox+ring = 107us
//   regression vs ~65us).

#define N_VOX 120000
#define IC 32
#define OC 64
#define NKV 27
#define DZ 21
#define HY 200
#define WX 176
#define TBL_BITS 20
#define TBL_SIZE (1 << TBL_BITS)
#define TBL_MASK (TBL_SIZE - 1)
#define MAXROWS 480000
#define SPILLCAP 65536

// ws layout (bytes); R1 passing proved ws_size >= 144,228,864
#define OFF_KEYS 0                 // 4,194,304
#define OFF_VALS 4194304           // 4,194,304
#define OFF_CNT 8388608            // 256 (cnt[0]=rows, cnt[1]=spill)
#define OFF_ROWS 8388864           // 12,960,000
#define OFF_FEATB 21348864         // 7,680,000
#define OFF_W2T 29028864           // 110,592
#define OFF_W1T 29139456           // 110,592
#define OFF_SPILL 29250048         // 524,288
#define OFF_INVM 29774336          // 1,920,000  per-row kv bitmask
#define OFF_CNT2 31694336          // 1,920,000  per-row slot counter
#define OFF_INV2 33614336          // 7,680,000  inv2[4][MAXROWS]
#define OFF_GRID 81614336          // 61,440,000
#define WS_NEEDED (OFF_GRID + (size_t)MAXROWS * OC * 2)  // 143,054,336

typedef __attribute__((ext_vector_type(8))) short short8;
typedef __attribute__((ext_vector_type(4))) float f32x4;

__device__ __forceinline__ uint32_t hash_lin(int lin) {
    return ((uint32_t)lin * 2654435761u) >> (32 - TBL_BITS);
}

__device__ __forceinline__ void atomPkBf16(uint16_t* p, uint32_t v) {
    asm volatile("global_atomic_pk_add_bf16 %0, %1, off" :: "v"(p), "v"(v) : "memory");
}

// RTNE f32 -> bf16 pair pack
__device__ __forceinline__ uint32_t pk_bf16(float a, float b) {
    uint32_t x = __float_as_uint(a), y = __float_as_uint(b);
    x = (x + 0x7fffu + ((x >> 16) & 1u)) >> 16;
    y = (y + 0x7fffu + ((y >> 16) & 1u)) >> 16;
    return x | (y << 16);
}
__device__ __forceinline__ uint16_t f2bf(float a) {
    uint32_t x = __float_as_uint(a);
    return (uint16_t)((x + 0x7fffu + ((x >> 16) & 1u)) >> 16);
}
__device__ __forceinline__ float bf2f(uint16_t u) {
    return __uint_as_float(((uint32_t)u) << 16);
}

__global__ void k_init(int* keys, int* counter,
                       const float2* __restrict__ feat2, uint32_t* featb,
                       const float* __restrict__ W1, uint16_t* w1t,
                       const float* __restrict__ W2, uint16_t* w2t) {
    int i = blockIdx.x * blockDim.x + threadIdx.x;
    int stride = gridDim.x * blockDim.x;
    for (int j = i; j < TBL_SIZE; j += stride) keys[j] = -1;
    for (int j = i; j < N_VOX * IC / 2; j += stride) {
        float2 f = feat2[j];
        featb[j] = pk_bf16(f.x, f.y);
    }
    // W1 [kv][c][o] f32 -> w1t [kv][o][c] bf16
    for (int j = i; j < NKV * IC * OC; j += stride) {
        int kv = j >> 11, c = (j >> 6) & 31, o = j & 63;
        w1t[(kv << 11) + (o << 5) + c] = f2bf(W1[j]);
    }
    // W2 [kv][o][c] f32 -> w2t [kv][c][o] bf16
    for (int j = i; j < NKV * OC * IC; j += stride) {
        int kv = j >> 11, o = (j >> 5) & 63, c = j & 31;
        w2t[(kv << 11) + (c << 6) + o] = f2bf(W2[j]);
    }
    if (i == 0) { counter[0] = 0; counter[1] = 0; }
}

__global__ void k_build(const int* __restrict__ coors, int* keys, int* rows) {
    int v = blockIdx.x * blockDim.x + threadIdx.x;
    if (v >= N_VOX) return;
    int b = coors[v * 4 + 0];
    int z = coors[v * 4 + 1];
    int y = coors[v * 4 + 2];
    int x = coors[v * 4 + 3];
#pragma unroll
    for (int kv = 0; kv < NKV; ++kv) {
        int oz = kv / 9, oy = (kv / 3) % 3, ox = kv % 3;
        int az = z + 1 - oz, ay = y + 1 - oy, ax = x + 1 - ox;
        int slot = -1;
        bool valid = (az >= 0) && !(az & 1) && ((az >> 1) < DZ) &&
                     (ay >= 0) && !(ay & 1) && ((ay >> 1) < HY) &&
                     (ax >= 0) && !(ax & 1) && ((ax >> 1) < WX);
        if (valid) {
            int lin = ((b * DZ + (az >> 1)) * HY + (ay >> 1)) * WX + (ax >> 1);
            uint32_t h = hash_lin(lin);
            for (;;) {
                int k = atomicCAS(&keys[h], -1, lin);
                if (k == -1 || k == lin) { slot = (int)h; break; }
                h = (h + 1) & TBL_MASK;
            }
        }
        rows[kv * N_VOX + v] = slot;
    }
}

// Block-aggregated compaction (1 atomic/block) + fused init of the block's
// claimed rows' pack arrays (invm=0, cnt2=0, inv2 slots=-1).
__global__ __launch_bounds__(256) void k_assign(const int* __restrict__ keys,
                                                int* __restrict__ vals,
                                                int* counter,
                                                uint32_t* __restrict__ invm,
                                                int* __restrict__ cnt2,
                                                int* __restrict__ inv2) {
    const int t = threadIdx.x;
    const int s0 = blockIdx.x * 2048 + t * 8;
    const int4 a = ((const int4*)(keys + s0))[0];
    const int4 b = ((const int4*)(keys + s0))[1];
    int k[8] = {a.x, a.y, a.z, a.w, b.x, b.y, b.z, b.w};
    int c = 0;
#pragma unroll
    for (int i = 0; i < 8; ++i) c += (k[i] != -1);

    __shared__ int sc[256];
    __shared__ int base;
    sc[t] = c;
    __syncthreads();
#pragma unroll
    for (int d = 1; d < 256; d <<= 1) {
        int y = (t >= d) ? sc[t - d] : 0;
        __syncthreads();
        sc[t] += y;
        __syncthreads();
    }
    if (t == 255) base = atomicAdd(&counter[0], sc[255]);
    __syncthreads();
    const int total = sc[255];
    int r = base + sc[t] - c;  // exclusive prefix
#pragma unroll
    for (int i = 0; i < 8; ++i) {
        if (k[i] != -1) { vals[s0 + i] = (r < MAXROWS) ? r : -1; ++r; }
    }
    int zs = min(base, MAXROWS), ze = min(base + total, MAXROWS);
    for (int i = zs + t; i < ze; i += 256) {
        invm[i] = 0u;
        cnt2[i] = 0;
        inv2[0 * MAXROWS + i] = -1;
        inv2[1 * MAXROWS + i] = -1;
        inv2[2 * MAXROWS + i] = -1;
        inv2[3 * MAXROWS + i] = -1;
    }
}

// rows slot->rowid rewrite FUSED with packed-contributor build.
// atomicOr detects duplicate-kv (same (row,kv) twice = duplicate coords);
// atomicAdd claims a slot; >4 distinct kvs overflow -> spill.
__global__ void k_rows_fix(int* rows, const int* __restrict__ vals,
                           uint32_t* invm, int* cnt2, int* inv2,
                           int* spill, int* counter) {
    int i = blockIdx.x * blockDim.x + threadIdx.x;
    if (i >= NKV * N_VOX) return;
    int s = rows[i];
    int row = (s >= 0) ? vals[s] : -1;
    rows[i] = row;
    if (row >= 0) {
        int kv = i / N_VOX;
        int v = i - kv * N_VOX;
        uint32_t bit = 1u << kv;
        uint32_t old = atomicOr(&invm[row], bit);
        bool ok = false;
        if (!(old & bit)) {
            int idx = atomicAdd(&cnt2[row], 1);
            if (idx < 4) {
                inv2[idx * MAXROWS + row] = (kv << 20) | v;
                ok = true;
            }
        }
        if (!ok) {  // duplicate-kv or slot overflow
            int sp = atomicAdd(&counter[1], 1);
            if (sp < SPILLCAP) {
                spill[2 * sp] = row;
                spill[2 * sp + 1] = (kv << 20) | v;
            }
        }
    }
}

// Scatter, OUTPUT-major MFMA, pack-preloaded. Wave owns 16 grid rows.
// Load 4 slot entries (coalesced) -> issue ALL feat gathers upfront into
// statically-indexed regs -> union-kv mask via shfl_xor OR -> while(mask):
// select matching frag (cndmask), 4 MFMAs. No loads gate MFMAs except W1 (L1).
// D: col(li)=channel nt*16+li, row(lg*4+rg)=grid row.
__global__ __launch_bounds__(256) void k_scatter_o(
    const uint16_t* __restrict__ featb, const uint16_t* __restrict__ w1t,
    const int* __restrict__ inv2, const int* __restrict__ counter,
    uint16_t* __restrict__ gridb) {
    const int wid = threadIdx.x >> 6;
    const int lane = threadIdx.x & 63;
    const int nrows = min(counter[0], MAXROWS);
    const int g0 = (blockIdx.x * 4 + wid) * 16;
    if (g0 >= nrows) return;
    const int lg = lane >> 4;
    const int li = lane & 15;
    const bool rowok = (g0 + li) < nrows;
    const short8 zz8 = {0, 0, 0, 0, 0, 0, 0, 0};

    // 4 packed entries for this lane's row (each plane coalesced 64B/tile)
    const int e0 = rowok ? inv2[0 * MAXROWS + g0 + li] : -1;
    const int e1 = rowok ? inv2[1 * MAXROWS + g0 + li] : -1;
    const int e2 = rowok ? inv2[2 * MAXROWS + g0 + li] : -1;
    const int e3 = rowok ? inv2[3 * MAXROWS + g0 + li] : -1;

    // preload ALL contributor feat fragments (independent, latency paid once)
    short8 a0 = zz8, a1 = zz8, a2 = zz8, a3 = zz8;
    if (e0 >= 0) a0 = *(const short8*)(featb + (size_t)(e0 & 0xFFFFF) * IC + lg * 8);
    if (e1 >= 0) a1 = *(const short8*)(featb + (size_t)(e1 & 0xFFFFF) * IC + lg * 8);
    if (e2 >= 0) a2 = *(const short8*)(featb + (size_t)(e2 & 0xFFFFF) * IC + lg * 8);
    if (e3 >= 0) a3 = *(const short8*)(featb + (size_t)(e3 & 0xFFFFF) * IC + lg * 8);

    // per-lane kv mask -> union across the 16 rows (butterfly OR)
    uint32_t m = 0;
    if (e0 >= 0) m |= 1u << (e0 >> 20);
    if (e1 >= 0) m |= 1u << (e1 >> 20);
    if (e2 >= 0) m |= 1u << (e2 >> 20);
    if (e3 >= 0) m |= 1u << (e3 >> 20);
    m |= __shfl_xor(m, 1, 64);
    m |= __shfl_xor(m, 2, 64);
    m |= __shfl_xor(m, 4, 64);
    m |= __shfl_xor(m, 8, 64);

    f32x4 acc[4] = {{0.f, 0.f, 0.f, 0.f}, {0.f, 0.f, 0.f, 0.f},
                    {0.f, 0.f, 0.f, 0.f}, {0.f, 0.f, 0.f, 0.f}};

    while (m) {
        const int kv = __builtin_ctz(m);
        m &= m - 1;
        short8 a = zz8;
        a = (e0 >= 0 && (e0 >> 20) == kv) ? a0 : a;
        a = (e1 >= 0 && (e1 >> 20) == kv) ? a1 : a;
        a = (e2 >= 0 && (e2 >> 20) == kv) ? a2 : a;
        a = (e3 >= 0 && (e3 >> 20) == kv) ? a3 : a;
        const uint16_t* w1k = w1t + (kv << 11);
#pragma unroll
        for (int nt = 0; nt < 4; ++nt) {
            const short8 b = *(const short8*)(w1k + (nt * 16 + li) * IC + lg * 8);
            acc[nt] = __builtin_amdgcn_mfma_f32_16x16x32_bf16(a, b, acc[nt], 0, 0, 0);
        }
    }
#pragma unroll
    for (int nt = 0; nt < 4; ++nt) {
#pragma unroll
        for (int rg = 0; rg < 4; ++rg) {
            const int g = g0 + lg * 4 + rg;
            float other = __shfl_xor(acc[nt][rg], 1, 64);
            if ((li & 1) == 0 && g < nrows) {
                *(uint32_t*)(gridb + (size_t)g * OC + nt * 16 + li) =
                    pk_bf16(acc[nt][rg], other);
            }
        }
    }
}

// Apply spilled (dup-kv / overflow) contributions atomically AFTER the store
// pass. ~3K entries expected; one wave per entry, lane = out channel.
__global__ void k_spill(const uint16_t* __restrict__ featb,
                        const uint16_t* __restrict__ w1t,
                        const int* __restrict__ spill,
                        const int* __restrict__ counter,
                        uint16_t* gridb) {
    const int nspill = min(counter[1], SPILLCAP);
    const int lane = threadIdx.x & 63;
    const int wstride = gridDim.x * (blockDim.x >> 6);
    for (int s = blockIdx.x * (blockDim.x >> 6) + (threadIdx.x >> 6);
         s < nspill; s += wstride) {
        const int row = spill[2 * s];
        const int kvv = spill[2 * s + 1];
        const int kv = kvv >> 20;
        const int v = kvv & 0xFFFFF;
        const uint16_t* f = featb + (size_t)v * IC;
        const uint16_t* wr = w1t + (kv << 11) + lane * IC;
        float acc = 0.f;
#pragma unroll
        for (int c = 0; c < IC; ++c) acc += bf2f(f[c]) * bf2f(wr[c]);
        float other = __shfl_xor(acc, 1, 64);
        if ((lane & 1) == 0)
            atomPkBf16(gridb + (size_t)row * OC + lane, pk_bf16(acc, other));
    }
}

// Gather, v-major MFMA (R6/R13-proven form). Wave owns 32 voxels; loops 27 kv;
// masked A-loads of grid rows + W2^T B-frags; f32 accum; one plain store.
__global__ __launch_bounds__(256) void k_gather_v(
    const uint16_t* __restrict__ gridb, const uint16_t* __restrict__ w2t,
    const int* __restrict__ rows, float* __restrict__ out) {
    const int wid = threadIdx.x >> 6;
    const int lane = threadIdx.x & 63;
    const int v0 = (blockIdx.x * 4 + wid) * 32;
    if (v0 >= N_VOX) return;
    const int lg = lane >> 4;
    const int li = lane & 15;

    f32x4 acc[2][2] = {{{0.f, 0.f, 0.f, 0.f}, {0.f, 0.f, 0.f, 0.f}},
                       {{0.f, 0.f, 0.f, 0.f}, {0.f, 0.f, 0.f, 0.f}}};

    for (int kv = 0; kv < NKV; ++kv) {
        const int* rkv = rows + kv * N_VOX;
        const uint16_t* w2k = w2t + ((size_t)kv << 11);
        short8 b[2][2];  // [ntile][khalf]
#pragma unroll
        for (int nt = 0; nt < 2; ++nt)
#pragma unroll
            for (int kh = 0; kh < 2; ++kh)
                b[nt][kh] = *(const short8*)(w2k + (nt * 16 + li) * 64 +
                                             kh * 32 + lg * 8);
#pragma unroll
        for (int mt = 0; mt < 2; ++mt) {
            const int v = v0 + mt * 16 + li;
            const int r = rkv[v];
            short8 a0 = {0, 0, 0, 0, 0, 0, 0, 0};
            short8 a1 = {0, 0, 0, 0, 0, 0, 0, 0};
            if (r >= 0) {
                const uint16_t* gr = gridb + (size_t)r * OC;
                a0 = *(const short8*)(gr + lg * 8);        // k = 0..31
                a1 = *(const short8*)(gr + 32 + lg * 8);   // k = 32..63
            }
            acc[mt][0] = __builtin_amdgcn_mfma_f32_16x16x32_bf16(a0, b[0][0], acc[mt][0], 0, 0, 0);
            acc[mt][0] = __builtin_amdgcn_mfma_f32_16x16x32_bf16(a1, b[0][1], acc[mt][0], 0, 0, 0);
            acc[mt][1] = __builtin_amdgcn_mfma_f32_16x16x32_bf16(a0, b[1][0], acc[mt][1], 0, 0, 0);
            acc[mt][1] = __builtin_amdgcn_mfma_f32_16x16x32_bf16(a1, b[1][1], acc[mt][1], 0, 0, 0);
        }
    }
#pragma unroll
    for (int mt = 0; mt < 2; ++mt)
#pragma unroll
        for (int nt = 0; nt < 2; ++nt)
#pragma unroll
            for (int rg = 0; rg < 4; ++rg) {
                const int v = v0 + mt * 16 + lg * 4 + rg;
                out[(size_t)v * IC + nt * 16 + li] = acc[mt][nt][rg];
            }
}

extern "C" void kernel_launch(void* const* d_in, const int* in_sizes, int n_in,
                              void* d_out, int out_size, void* d_ws, size_t ws_size,
                              hipStream_t stream) {
    const float* feat = (const float*)d_in[0];
    const int* coors = (const int*)d_in[1];
    const float* W1 = (const float*)d_in[2];
    const float* W2 = (const float*)d_in[3];
    float* out = (float*)d_out;

    if (ws_size < WS_NEEDED) return;  // loud failure: out stays poisoned

    char* ws = (char*)d_ws;
    int* keys = (int*)(ws + OFF_KEYS);
    int* vals = (int*)(ws + OFF_VALS);
    int* counter = (int*)(ws + OFF_CNT);
    int* rows = (int*)(ws + OFF_ROWS);
    uint32_t* featb = (uint32_t*)(ws + OFF_FEATB);
    uint16_t* w2t = (uint16_t*)(ws + OFF_W2T);
    uint16_t* w1t = (uint16_t*)(ws + OFF_W1T);
    int* spill = (int*)(ws + OFF_SPILL);
    uint32_t* invm = (uint32_t*)(ws + OFF_INVM);
    int* cnt2 = (int*)(ws + OFF_CNT2);
    int* inv2 = (int*)(ws + OFF_INV2);
    uint16_t* gridb = (uint16_t*)(ws + OFF_GRID);

    k_init<<<dim3(4096), dim3(256), 0, stream>>>(keys, counter,
                                                 (const float2*)feat, featb,
                                                 W1, w1t, W2, w2t);
    k_build<<<dim3((N_VOX + 255) / 256), dim3(256), 0, stream>>>(coors, keys, rows);
    k_assign<<<dim3(TBL_SIZE / 2048), dim3(256), 0, stream>>>(keys, vals, counter,
                                                              invm, cnt2, inv2);
    k_rows_fix<<<dim3((NKV * N_VOX + 255) / 256), dim3(256), 0, stream>>>(
        rows, vals, invm, cnt2, inv2, spill, counter);
    // output-major scatter: 16 rows/wave, 4 waves/block over MAXROWS
    k_scatter_o<<<dim3(MAXROWS / 64), dim3(256), 0, stream>>>(
        (const uint16_t*)featb, w1t, inv2, counter, gridb);
    k_spill<<<dim3(64), dim3(256), 0, stream>>>((const uint16_t*)featb, w1t,
                                                spill, counter, gridb);
    // gather: 32 vox/wave, 4 waves/block
    k_gather_v<<<dim3((N_VOX + 127) / 128), dim3(256), 0, stream>>>(gridb, w2t,
                                                                    rows, out);
}